// Round 8
// baseline (4565.764 us; speedup 1.0000x reference)
//
#include <hip/hip_runtime.h>
#include <hip/hip_bf16.h>
#include <cstdint>
#include <cstddef>

typedef __attribute__((ext_vector_type(8))) short short8;
typedef __attribute__((ext_vector_type(4))) short short4v;
typedef __attribute__((ext_vector_type(4))) float floatx4;
typedef unsigned short ushort_t;

#define LOG2E 1.44269504088896340736f

__device__ __forceinline__ unsigned short f2bf(float f) {
    unsigned u = __float_as_uint(f);
    u += 0x7FFFu + ((u >> 16) & 1u);   // RNE
    return (unsigned short)(u >> 16);
}
__device__ __forceinline__ float bf2f(unsigned short s) {
    return __uint_as_float(((unsigned)s) << 16);
}

// ---------------------------------------------------------------------------
// wprep: W fp32 (256x256) -> bf16 once.
// ---------------------------------------------------------------------------
__global__ __launch_bounds__(256) void wprep(const float* __restrict__ W,
                                             ushort_t* __restrict__ Wb) {
    int t = blockIdx.x * 256 + threadIdx.x;   // 16384 float4s
    float4 v = ((const float4*)W)[t];
    short4v s;
    s[0] = (short)f2bf(v.x); s[1] = (short)f2bf(v.y);
    s[2] = (short)f2bf(v.z); s[3] = (short)f2bf(v.w);
    ((short4v*)Wb)[t] = s;
}

// ---------------------------------------------------------------------------
// gemm_h: h[b][j][o] = sum_k x[b][j][k]*W[o][k], stored TILED:
//   hT2[b][j/32][o][j%32]  (bf16) -- so attn's A-frags are wave-contiguous.
// Block = 64 j x 256 o. x staged via 16 coalesced float4 passes -> bf16 ->
// LDS. W staged in LDS in four K-quarters.
// Epilogue: tiled hT store + s_src/s_dst (written once, no atomics).
// ---------------------------------------------------------------------------
__global__ __launch_bounds__(256) void gemm_h(const float* __restrict__ x,
                                              const ushort_t* __restrict__ Wb,
                                              ushort_t* __restrict__ hT,
                                              const float* __restrict__ a_src,
                                              const float* __restrict__ a_dst,
                                              float* __restrict__ s_src,
                                              float* __restrict__ s_dst) {
    const int tid = threadIdx.x;
    const int w = tid >> 6, lane = tid & 63;
    const int q = lane >> 4, t16 = lane & 15;

    __shared__ ushort_t xt[64][264];   // pitch 264 shorts = 528 B
    __shared__ ushort_t wt[256][72];   // pitch 72 shorts = 144 B

    // ---- stage x: 16 coalesced float4 passes (64*256 floats / (256thr*4)) ----
    const float* xblk = x + (size_t)blockIdx.x * 64 * 256;
    const int xrow_half = tid >> 6;          // 0..3
    const int xcol = (tid & 63) * 4;
#pragma unroll
    for (int p = 0; p < 16; ++p) {
        float4 v = *(const float4*)(xblk + p * 1024 + tid * 4);
        short4v s;
        s[0] = (short)f2bf(v.x); s[1] = (short)f2bf(v.y);
        s[2] = (short)f2bf(v.z); s[3] = (short)f2bf(v.w);
        *(short4v*)(&xt[p * 4 + xrow_half][xcol]) = s;
    }

    floatx4 acc[16] = {};
#pragma unroll
    for (int kq = 0; kq < 4; ++kq) {
        if (kq) __syncthreads();        // readers of wt done
        // stage W quarter: thread t covers o=t, 128B contiguous
#pragma unroll
        for (int g = 0; g < 8; ++g) {
            int4 wv = *(const int4*)(Wb + (size_t)tid * 256 + kq * 64 + g * 8);
            *(int4*)(&wt[tid][g * 8]) = wv;
        }
        __syncthreads();                // wt (and xt on kq==0) visible
#pragma unroll
        for (int ks = 0; ks < 2; ++ks) {
            short8 af = *(const short8*)(&xt[w * 16 + t16][kq * 64 + ks * 32 + q * 8]);
#pragma unroll
            for (int ct = 0; ct < 16; ++ct) {
                short8 bf = *(const short8*)(&wt[ct * 16 + t16][ks * 32 + q * 8]);
                acc[ct] = __builtin_amdgcn_mfma_f32_16x16x32_bf16(af, bf, acc[ct], 0, 0, 0);
            }
        }
    }

    // ---- hT store (tiled layout): D col=t16 -> o_local, row=q*4+r -> j_local
    const int jbase = blockIdx.x * 64 + w * 16 + q * 4;   // flat b*2048+j
    const int b = jbase >> 11, jj = jbase & 2047;
    const int tile = jj >> 5, col = jj & 31;
    ushort_t* hTt = hT + (((size_t)b * 64 + tile) * 256) * 32 + col;
#pragma unroll
    for (int ct = 0; ct < 16; ++ct) {
        const int o = ct * 16 + t16;
        short4v sv;
        sv[0] = (short)f2bf(acc[ct][0]);
        sv[1] = (short)f2bf(acc[ct][1]);
        sv[2] = (short)f2bf(acc[ct][2]);
        sv[3] = (short)f2bf(acc[ct][3]);
        *(short4v*)(hTt + (size_t)o * 32) = sv;
    }

    // ---- s_src/s_dst epilogue ----
    float psv[4] = {}, pdv[4] = {};
#pragma unroll
    for (int ct = 0; ct < 16; ++ct) {
        const int o = ct * 16 + t16;
        float as = a_src[o], ad = a_dst[o];
#pragma unroll
        for (int r = 0; r < 4; ++r) {
            psv[r] = __fmaf_rn(acc[ct][r], as, psv[r]);
            pdv[r] = __fmaf_rn(acc[ct][r], ad, pdv[r]);
        }
    }
#pragma unroll
    for (int m = 1; m < 16; m <<= 1) {
#pragma unroll
        for (int r = 0; r < 4; ++r) {
            psv[r] += __shfl_xor(psv[r], m);
            pdv[r] += __shfl_xor(pdv[r], m);
        }
    }
    if (t16 == 0) {
#pragma unroll
        for (int r = 0; r < 4; ++r) {
            s_src[jbase + r] = psv[r];
            s_dst[jbase + r] = pdv[r];
        }
    }
}

// ---------------------------------------------------------------------------
// attn: barrier-free, zero-LDS. Block = 32 i x 256 o (4 waves = 4 o-quarters,
// p duplicated across waves). Grid (b=8, 64) -> 512 blocks, 2/CU.
// Per 32-j chunk: A-frags = ONE contiguous 1KB wave-load per ct (tiled hT);
// p computed in-lane directly in B-frag layout from adj (coalesced 128B/row)
// + s scores; row sums via shfl; loads software-pipelined 2 chunks ahead.
// NOTE: score t = LOG2E*(s_src+s_dst) -- s_dst must also be scaled (fmaf);
// R5-R7 dropped it (the 0.082 absmax bug).
// ---------------------------------------------------------------------------
__global__ __launch_bounds__(256, 2) void attn(const ushort_t* __restrict__ hT,
                                               const int* __restrict__ adj,
                                               const float* __restrict__ s_src,
                                               const float* __restrict__ s_dst,
                                               float* __restrict__ out) {
    const int tid = threadIdx.x;
    const int w = tid >> 6, lane = tid & 63;
    const int q = lane >> 4, t16 = lane & 15;
    const int b = blockIdx.x;
    const int i0 = blockIdx.y * 32;
    const int oq = w * 64;

    float si[2];
    const int* adjp[2];
#pragma unroll
    for (int it = 0; it < 2; ++it) {
        const int i = i0 + it * 16 + t16;
        si[it] = s_src[(size_t)b * 2048 + i] * LOG2E;
        adjp[it] = adj + ((size_t)b * 2048 + i) * 2048 + q * 8;
    }
    const float* sdp = s_dst + (size_t)b * 2048 + q * 8;
    const ushort_t* hTp = hT + ((size_t)b * 16384 + oq + t16) * 32 + q * 8;
    // chunk c: +c*8192 ; ct: +ct*512

    floatx4 acc[4][2] = {};
    float lsum[2] = {0.f, 0.f};
    short8 af[2][4];
    int4 aj[2][2][2];    // [slot][it][half]
    short8 bfc[2];

    // preload chunk 0 -> slot 0
#pragma unroll
    for (int ct = 0; ct < 4; ++ct) af[0][ct] = *(const short8*)(hTp + ct * 512);
#pragma unroll
    for (int it = 0; it < 2; ++it) {
        aj[0][it][0] = *(const int4*)(adjp[it]);
        aj[0][it][1] = *(const int4*)(adjp[it] + 4);
    }
    // build bf chunk 0
    {
        float4 d0 = *(const float4*)(sdp);
        float4 d1 = *(const float4*)(sdp + 4);
        float sdv[8] = {d0.x, d0.y, d0.z, d0.w, d1.x, d1.y, d1.z, d1.w};
#pragma unroll
        for (int it = 0; it < 2; ++it) {
            int mv[8] = {aj[0][it][0].x, aj[0][it][0].y, aj[0][it][0].z, aj[0][it][0].w,
                         aj[0][it][1].x, aj[0][it][1].y, aj[0][it][1].z, aj[0][it][1].w};
            short8 pv;
#pragma unroll
            for (int e = 0; e < 8; ++e) {
                float t = __fmaf_rn(sdv[e], LOG2E, si[it]);   // LOG2E*(ss+sd)
                float lr = fmaxf(t, 0.2f * t);
                float pe = __builtin_amdgcn_exp2f(lr);
                pe = (mv[e] != 0) ? pe : 0.0f;
                unsigned short u = f2bf(pe);
                lsum[it] += bf2f(u);
                pv[e] = (short)u;
            }
            bfc[it] = pv;
        }
    }
    // issue chunk 1 -> slot 1
#pragma unroll
    for (int ct = 0; ct < 4; ++ct) af[1][ct] = *(const short8*)(hTp + 8192 + ct * 512);
#pragma unroll
    for (int it = 0; it < 2; ++it) {
        aj[1][it][0] = *(const int4*)(adjp[it] + 32);
        aj[1][it][1] = *(const int4*)(adjp[it] + 36);
    }

    for (int c = 0; c < 64; ++c) {
        const int s = c & 1, sn = s ^ 1;
        // 1) MFMA chunk c
#pragma unroll
        for (int ct = 0; ct < 4; ++ct) {
            acc[ct][0] = __builtin_amdgcn_mfma_f32_16x16x32_bf16(af[s][ct], bfc[0], acc[ct][0], 0, 0, 0);
            acc[ct][1] = __builtin_amdgcn_mfma_f32_16x16x32_bf16(af[s][ct], bfc[1], acc[ct][1], 0, 0, 0);
        }
        // 2) issue loads for chunk c+2 into slot s (af[s] dead after MFMA issue)
        if (c + 2 < 64) {
            const ushort_t* hp = hTp + (size_t)(c + 2) * 8192;
#pragma unroll
            for (int ct = 0; ct < 4; ++ct) af[s][ct] = *(const short8*)(hp + ct * 512);
#pragma unroll
            for (int it = 0; it < 2; ++it) {
                aj[s][it][0] = *(const int4*)(adjp[it] + (c + 2) * 32);
                aj[s][it][1] = *(const int4*)(adjp[it] + (c + 2) * 32 + 4);
            }
        }
        // 3) build bf for chunk c+1 from slot sn (issued one full iter ago)
        if (c + 1 < 64) {
            float4 d0 = *(const float4*)(sdp + (c + 1) * 32);
            float4 d1 = *(const float4*)(sdp + (c + 1) * 32 + 4);
            float sdv[8] = {d0.x, d0.y, d0.z, d0.w, d1.x, d1.y, d1.z, d1.w};
#pragma unroll
            for (int it = 0; it < 2; ++it) {
                int mv[8] = {aj[sn][it][0].x, aj[sn][it][0].y, aj[sn][it][0].z, aj[sn][it][0].w,
                             aj[sn][it][1].x, aj[sn][it][1].y, aj[sn][it][1].z, aj[sn][it][1].w};
                short8 pv;
#pragma unroll
                for (int e = 0; e < 8; ++e) {
                    float t = __fmaf_rn(sdv[e], LOG2E, si[it]);   // LOG2E*(ss+sd)
                    float lr = fmaxf(t, 0.2f * t);
                    float pe = __builtin_amdgcn_exp2f(lr);
                    pe = (mv[e] != 0) ? pe : 0.0f;
                    unsigned short u = f2bf(pe);
                    lsum[it] += bf2f(u);
                    pv[e] = (short)u;
                }
                bfc[it] = pv;
            }
        }
    }

    // reduce l over the 4 q-lane groups (lanes q*16+t16 share (it,t16))
#pragma unroll
    for (int it = 0; it < 2; ++it) {
        float l = lsum[it];
        l += __shfl_xor(l, 16);
        l += __shfl_xor(l, 32);
        lsum[it] = (l > 0.f) ? 1.0f / l : 0.0f;
    }

    // epilogue: D col=t16 -> i_local, row=q*4+r -> o_local
#pragma unroll
    for (int it = 0; it < 2; ++it) {
        const float rl = lsum[it];
        float* orow = out + ((size_t)b * 2048 + i0 + it * 16 + t16) * 256 + oq + q * 4;
#pragma unroll
        for (int ct = 0; ct < 4; ++ct) {
            floatx4 v = acc[ct][it] * rl;
            *(floatx4*)(orow + ct * 16) = v;
        }
    }
}

extern "C" void kernel_launch(void* const* d_in, const int* in_sizes, int n_in,
                              void* d_out, int out_size, void* d_ws, size_t ws_size,
                              hipStream_t stream) {
    const float* x     = (const float*)d_in[0];
    const int*   adj   = (const int*)d_in[1];
    const float* W     = (const float*)d_in[2];
    const float* a_src = (const float*)d_in[3];
    const float* a_dst = (const float*)d_in[4];
    float* out = (float*)d_out;

    // 8.25 MB scratch (proven footprint)
    char* ws = (char*)d_ws;
    ushort_t* hT = (ushort_t*)ws;                                   // [0, 8M)
    float* s_src = (float*)(ws + (size_t)8 * 1024 * 1024);          // 64 KB
    float* s_dst = s_src + 16384;                                   // 64 KB
    ushort_t* Wb = (ushort_t*)(s_dst + 16384);                      // 128 KB

    wprep<<<64, 256, 0, stream>>>(W, Wb);
    gemm_h<<<256, 256, 0, stream>>>(x, Wb, hT, a_src, a_dst, s_src, s_dst);
    attn<<<dim3(8, 64), 256, 0, stream>>>(hT, adj, s_src, s_dst, out);
}

// Round 9
// 298.721 us; speedup vs baseline: 15.2844x; 15.2844x over previous
//
#include <hip/hip_runtime.h>
#include <hip/hip_bf16.h>
#include <cstdint>
#include <cstddef>

typedef __attribute__((ext_vector_type(8))) short short8;
typedef __attribute__((ext_vector_type(4))) short short4v;
typedef __attribute__((ext_vector_type(4))) float floatx4;
typedef unsigned short ushort_t;

#define LOG2E 1.44269504088896340736f

__device__ __forceinline__ unsigned short f2bf(float f) {
    unsigned u = __float_as_uint(f);
    u += 0x7FFFu + ((u >> 16) & 1u);   // RNE
    return (unsigned short)(u >> 16);
}
__device__ __forceinline__ float bf2f(unsigned short s) {
    return __uint_as_float(((unsigned)s) << 16);
}

// ---------------------------------------------------------------------------
// wprep: W fp32 (256x256) -> bf16 once.
// ---------------------------------------------------------------------------
__global__ __launch_bounds__(256) void wprep(const float* __restrict__ W,
                                             ushort_t* __restrict__ Wb) {
    int t = blockIdx.x * 256 + threadIdx.x;   // 16384 float4s
    float4 v = ((const float4*)W)[t];
    short4v s;
    s[0] = (short)f2bf(v.x); s[1] = (short)f2bf(v.y);
    s[2] = (short)f2bf(v.z); s[3] = (short)f2bf(v.w);
    ((short4v*)Wb)[t] = s;
}

// ---------------------------------------------------------------------------
// gemm_h: h[b][j][o] = sum_k x[b][j][k]*W[o][k], stored TILED:
//   hT2[b][j/32][o][j%32]  (bf16) -- so attn's A-frags are wave-contiguous.
// Block = 64 j x 256 o. x staged via 16 coalesced float4 passes -> bf16 ->
// LDS. W staged in LDS in four K-quarters.
// Epilogue: tiled hT store + s_src/s_dst (written once, no atomics).
// ---------------------------------------------------------------------------
__global__ __launch_bounds__(256) void gemm_h(const float* __restrict__ x,
                                              const ushort_t* __restrict__ Wb,
                                              ushort_t* __restrict__ hT,
                                              const float* __restrict__ a_src,
                                              const float* __restrict__ a_dst,
                                              float* __restrict__ s_src,
                                              float* __restrict__ s_dst) {
    const int tid = threadIdx.x;
    const int w = tid >> 6, lane = tid & 63;
    const int q = lane >> 4, t16 = lane & 15;

    __shared__ ushort_t xt[64][264];   // pitch 264 shorts = 528 B
    __shared__ ushort_t wt[256][72];   // pitch 72 shorts = 144 B

    // ---- stage x: 16 coalesced float4 passes ----
    const float* xblk = x + (size_t)blockIdx.x * 64 * 256;
    const int xrow_half = tid >> 6;          // 0..3
    const int xcol = (tid & 63) * 4;
#pragma unroll
    for (int p = 0; p < 16; ++p) {
        float4 v = *(const float4*)(xblk + p * 1024 + tid * 4);
        short4v s;
        s[0] = (short)f2bf(v.x); s[1] = (short)f2bf(v.y);
        s[2] = (short)f2bf(v.z); s[3] = (short)f2bf(v.w);
        *(short4v*)(&xt[p * 4 + xrow_half][xcol]) = s;
    }

    floatx4 acc[16] = {};
#pragma unroll
    for (int kq = 0; kq < 4; ++kq) {
        if (kq) __syncthreads();        // readers of wt done
#pragma unroll
        for (int g = 0; g < 8; ++g) {
            int4 wv = *(const int4*)(Wb + (size_t)tid * 256 + kq * 64 + g * 8);
            *(int4*)(&wt[tid][g * 8]) = wv;
        }
        __syncthreads();                // wt (and xt on kq==0) visible
#pragma unroll
        for (int ks = 0; ks < 2; ++ks) {
            short8 af = *(const short8*)(&xt[w * 16 + t16][kq * 64 + ks * 32 + q * 8]);
#pragma unroll
            for (int ct = 0; ct < 16; ++ct) {
                short8 bf = *(const short8*)(&wt[ct * 16 + t16][ks * 32 + q * 8]);
                acc[ct] = __builtin_amdgcn_mfma_f32_16x16x32_bf16(af, bf, acc[ct], 0, 0, 0);
            }
        }
    }

    // ---- hT store (tiled layout) ----
    const int jbase = blockIdx.x * 64 + w * 16 + q * 4;   // flat b*2048+j
    const int b = jbase >> 11, jj = jbase & 2047;
    const int tile = jj >> 5, col = jj & 31;
    ushort_t* hTt = hT + (((size_t)b * 64 + tile) * 256) * 32 + col;
#pragma unroll
    for (int ct = 0; ct < 16; ++ct) {
        const int o = ct * 16 + t16;
        short4v sv;
        sv[0] = (short)f2bf(acc[ct][0]);
        sv[1] = (short)f2bf(acc[ct][1]);
        sv[2] = (short)f2bf(acc[ct][2]);
        sv[3] = (short)f2bf(acc[ct][3]);
        *(short4v*)(hTt + (size_t)o * 32) = sv;
    }

    // ---- s_src/s_dst epilogue ----
    float psv[4] = {}, pdv[4] = {};
#pragma unroll
    for (int ct = 0; ct < 16; ++ct) {
        const int o = ct * 16 + t16;
        float as = a_src[o], ad = a_dst[o];
#pragma unroll
        for (int r = 0; r < 4; ++r) {
            psv[r] = __fmaf_rn(acc[ct][r], as, psv[r]);
            pdv[r] = __fmaf_rn(acc[ct][r], ad, pdv[r]);
        }
    }
#pragma unroll
    for (int m = 1; m < 16; m <<= 1) {
#pragma unroll
        for (int r = 0; r < 4; ++r) {
            psv[r] += __shfl_xor(psv[r], m);
            pdv[r] += __shfl_xor(pdv[r], m);
        }
    }
    if (t16 == 0) {
#pragma unroll
        for (int r = 0; r < 4; ++r) {
            s_src[jbase + r] = psv[r];
            s_dst[jbase + r] = pdv[r];
        }
    }
}

// ---------------------------------------------------------------------------
// bfc builder: all-scalar args -> guaranteed register-resident after inline.
// ---------------------------------------------------------------------------
__device__ __forceinline__ void build_bfc(float4 d0, float4 d1,
                                          int4 m0a, int4 m0b, int4 m1a, int4 m1b,
                                          float si0, float si1,
                                          short8& b0, short8& b1,
                                          float& l0, float& l1) {
    float sdv[8] = {d0.x, d0.y, d0.z, d0.w, d1.x, d1.y, d1.z, d1.w};
    int mv0[8] = {m0a.x, m0a.y, m0a.z, m0a.w, m0b.x, m0b.y, m0b.z, m0b.w};
    int mv1[8] = {m1a.x, m1a.y, m1a.z, m1a.w, m1b.x, m1b.y, m1b.z, m1b.w};
#pragma unroll
    for (int e = 0; e < 8; ++e) {
        float t0 = __fmaf_rn(sdv[e], LOG2E, si0);   // LOG2E*(ss+sd)
        float t1 = __fmaf_rn(sdv[e], LOG2E, si1);
        float p0 = __builtin_amdgcn_exp2f(fmaxf(t0, 0.2f * t0));
        float p1 = __builtin_amdgcn_exp2f(fmaxf(t1, 0.2f * t1));
        p0 = (mv0[e] != 0) ? p0 : 0.0f;
        p1 = (mv1[e] != 0) ? p1 : 0.0f;
        unsigned short u0 = f2bf(p0), u1 = f2bf(p1);
        l0 += bf2f(u0); l1 += bf2f(u1);
        b0[e] = (short)u0; b1[e] = (short)u1;
    }
}

// ---------------------------------------------------------------------------
// attn: barrier-free, zero-LDS, fully register-resident pipeline.
// Block = 32 i x 256 o (4 waves = 4 o-quarters). Grid (b=8, 64) -> 512 blocks.
// K-loop unrolled x2 with SEPARATE named slot variables (af0/aj0 even chunks,
// af1/aj1 odd) -- R8's dynamic slot index forced the operand arrays to
// scratch (2.3 GB HBM spill traffic, 4.4 ms). Constant indices -> VGPRs.
// ---------------------------------------------------------------------------
__global__ __launch_bounds__(256, 2) void attn(const ushort_t* __restrict__ hT,
                                               const int* __restrict__ adj,
                                               const float* __restrict__ s_src,
                                               const float* __restrict__ s_dst,
                                               float* __restrict__ out) {
    const int tid = threadIdx.x;
    const int w = tid >> 6, lane = tid & 63;
    const int q = lane >> 4, t16 = lane & 15;
    const int b = blockIdx.x;
    const int i0 = blockIdx.y * 32;
    const int oq = w * 64;

    float si0, si1;
    const int* adjp0;
    const int* adjp1;
    {
        const int ia = i0 + t16, ib = i0 + 16 + t16;
        si0 = s_src[(size_t)b * 2048 + ia] * LOG2E;
        si1 = s_src[(size_t)b * 2048 + ib] * LOG2E;
        adjp0 = adj + ((size_t)b * 2048 + ia) * 2048 + q * 8;
        adjp1 = adj + ((size_t)b * 2048 + ib) * 2048 + q * 8;
    }
    const float* sdp = s_dst + (size_t)b * 2048 + q * 8;
    const ushort_t* hTp = hT + ((size_t)b * 16384 + oq + t16) * 32 + q * 8;
    // chunk c: +c*8192 ; ct: +ct*512

    floatx4 acc[4][2] = {};
    float l0 = 0.f, l1 = 0.f;
    short8 af0[4], af1[4];
    int4 aj0_0a, aj0_0b, aj0_1a, aj0_1b;   // even-slot adj (it0/it1, halves)
    int4 aj1_0a, aj1_0b, aj1_1a, aj1_1b;   // odd-slot adj
    short8 bf0, bf1;

    // prologue: chunk 0 -> slot 0
#pragma unroll
    for (int ct = 0; ct < 4; ++ct) af0[ct] = *(const short8*)(hTp + ct * 512);
    aj0_0a = *(const int4*)(adjp0);     aj0_0b = *(const int4*)(adjp0 + 4);
    aj0_1a = *(const int4*)(adjp1);     aj0_1b = *(const int4*)(adjp1 + 4);
    build_bfc(*(const float4*)(sdp), *(const float4*)(sdp + 4),
              aj0_0a, aj0_0b, aj0_1a, aj0_1b, si0, si1, bf0, bf1, l0, l1);
    // chunk 1 -> slot 1
#pragma unroll
    for (int ct = 0; ct < 4; ++ct) af1[ct] = *(const short8*)(hTp + 8192 + ct * 512);
    aj1_0a = *(const int4*)(adjp0 + 32); aj1_0b = *(const int4*)(adjp0 + 36);
    aj1_1a = *(const int4*)(adjp1 + 32); aj1_1b = *(const int4*)(adjp1 + 36);

    for (int c = 0; c < 64; c += 2) {
        // ---- body A: chunk c (slot 0) ----
#pragma unroll
        for (int ct = 0; ct < 4; ++ct) {
            acc[ct][0] = __builtin_amdgcn_mfma_f32_16x16x32_bf16(af0[ct], bf0, acc[ct][0], 0, 0, 0);
            acc[ct][1] = __builtin_amdgcn_mfma_f32_16x16x32_bf16(af0[ct], bf1, acc[ct][1], 0, 0, 0);
        }
        if (c + 2 < 64) {   // prefetch chunk c+2 -> slot 0
            const ushort_t* hp = hTp + (size_t)(c + 2) * 8192;
#pragma unroll
            for (int ct = 0; ct < 4; ++ct) af0[ct] = *(const short8*)(hp + ct * 512);
            aj0_0a = *(const int4*)(adjp0 + (c + 2) * 32); aj0_0b = *(const int4*)(adjp0 + (c + 2) * 32 + 4);
            aj0_1a = *(const int4*)(adjp1 + (c + 2) * 32); aj0_1b = *(const int4*)(adjp1 + (c + 2) * 32 + 4);
        }
        // build bfc for chunk c+1 from slot-1 adj
        build_bfc(*(const float4*)(sdp + (c + 1) * 32), *(const float4*)(sdp + (c + 1) * 32 + 4),
                  aj1_0a, aj1_0b, aj1_1a, aj1_1b, si0, si1, bf0, bf1, l0, l1);

        // ---- body B: chunk c+1 (slot 1) ----
#pragma unroll
        for (int ct = 0; ct < 4; ++ct) {
            acc[ct][0] = __builtin_amdgcn_mfma_f32_16x16x32_bf16(af1[ct], bf0, acc[ct][0], 0, 0, 0);
            acc[ct][1] = __builtin_amdgcn_mfma_f32_16x16x32_bf16(af1[ct], bf1, acc[ct][1], 0, 0, 0);
        }
        if (c + 3 < 64) {   // prefetch chunk c+3 -> slot 1
            const ushort_t* hp = hTp + (size_t)(c + 3) * 8192;
#pragma unroll
            for (int ct = 0; ct < 4; ++ct) af1[ct] = *(const short8*)(hp + ct * 512);
            aj1_0a = *(const int4*)(adjp0 + (c + 3) * 32); aj1_0b = *(const int4*)(adjp0 + (c + 3) * 32 + 4);
            aj1_1a = *(const int4*)(adjp1 + (c + 3) * 32); aj1_1b = *(const int4*)(adjp1 + (c + 3) * 32 + 4);
        }
        if (c + 2 < 64) {   // build bfc for chunk c+2 from slot-0 adj
            build_bfc(*(const float4*)(sdp + (c + 2) * 32), *(const float4*)(sdp + (c + 2) * 32 + 4),
                      aj0_0a, aj0_0b, aj0_1a, aj0_1b, si0, si1, bf0, bf1, l0, l1);
        }
    }

    // reduce l over the 4 q-lane groups (lanes q*16+t16 share (it,t16))
    l0 += __shfl_xor(l0, 16); l0 += __shfl_xor(l0, 32);
    l1 += __shfl_xor(l1, 16); l1 += __shfl_xor(l1, 32);
    const float rl0 = (l0 > 0.f) ? 1.0f / l0 : 0.0f;
    const float rl1 = (l1 > 0.f) ? 1.0f / l1 : 0.0f;

    // epilogue: D col=t16 -> i_local, row=q*4+r -> o_local
    float* orow0 = out + ((size_t)b * 2048 + i0 + t16) * 256 + oq + q * 4;
    float* orow1 = out + ((size_t)b * 2048 + i0 + 16 + t16) * 256 + oq + q * 4;
#pragma unroll
    for (int ct = 0; ct < 4; ++ct) {
        floatx4 v0 = acc[ct][0] * rl0;
        floatx4 v1 = acc[ct][1] * rl1;
        *(floatx4*)(orow0 + ct * 16) = v0;
        *(floatx4*)(orow1 + ct * 16) = v1;
    }
}

extern "C" void kernel_launch(void* const* d_in, const int* in_sizes, int n_in,
                              void* d_out, int out_size, void* d_ws, size_t ws_size,
                              hipStream_t stream) {
    const float* x     = (const float*)d_in[0];
    const int*   adj   = (const int*)d_in[1];
    const float* W     = (const float*)d_in[2];
    const float* a_src = (const float*)d_in[3];
    const float* a_dst = (const float*)d_in[4];
    float* out = (float*)d_out;

    // 8.25 MB scratch (proven footprint)
    char* ws = (char*)d_ws;
    ushort_t* hT = (ushort_t*)ws;                                   // [0, 8M)
    float* s_src = (float*)(ws + (size_t)8 * 1024 * 1024);          // 64 KB
    float* s_dst = s_src + 16384;                                   // 64 KB
    ushort_t* Wb = (ushort_t*)(s_dst + 16384);                      // 128 KB

    wprep<<<64, 256, 0, stream>>>(W, Wb);
    gemm_h<<<256, 256, 0, stream>>>(x, Wb, hT, a_src, a_dst, s_src, s_dst);
    attn<<<dim3(8, 64), 256, 0, stream>>>(hT, adj, s_src, s_dst, out);
}